// Round 16
// baseline (295.888 us; speedup 1.0000x reference)
//
#include <hip/hip_runtime.h>

typedef __attribute__((ext_vector_type(8))) short s8v;     // 8 x bf16 bits
typedef __attribute__((ext_vector_type(4))) float f4v;     // 4 x f32

#define MFMA16(a, b, c) __builtin_amdgcn_mfma_f32_16x16x32_bf16(a, b, c, 0, 0, 0)

__device__ __forceinline__ unsigned short f2bf(float f) {
    union { float f; unsigned int u; } v; v.f = f;
    unsigned int u = v.u;
    unsigned int r = (u + 0x7FFFu + ((u >> 16) & 1u)) >> 16;  // RNE
    return (unsigned short)r;
}

__device__ __forceinline__ unsigned int cvt_pk_bf16(float lo, float hi) {
    unsigned int r;
    asm volatile("v_cvt_pk_bf16_f32 %0, %1, %2" : "=v"(r) : "v"(lo), "v"(hi));
    return r;
}

// global -> LDS async copy, 16B per lane; LDS dest = wave-uniform base + lane*16
__device__ __forceinline__ void gl16(const void* g, void* l) {
    __builtin_amdgcn_global_load_lds(
        (const __attribute__((address_space(1))) void*)g,
        (__attribute__((address_space(3))) void*)l, 16, 0, 0);
}

// ---------------------------------------------------------------------------
// Kernel 0: activation convert fp32 -> bf16 (query/key/value), vectorized x8
// ---------------------------------------------------------------------------
__global__ __launch_bounds__(256) void cvt_bf16_k(
        const float* __restrict__ X0, const float* __restrict__ X1,
        const float* __restrict__ X2,
        unsigned short* __restrict__ Y0, unsigned short* __restrict__ Y1,
        unsigned short* __restrict__ Y2) {
    const float* X; unsigned short* Y;
    switch (blockIdx.y) {
        case 0:  X = X0; Y = Y0; break;
        case 1:  X = X1; Y = Y1; break;
        default: X = X2; Y = Y2; break;
    }
    size_t i = ((size_t)blockIdx.x * 256 + threadIdx.x) * 8;
    float4 a = *reinterpret_cast<const float4*>(X + i);
    float4 b = *reinterpret_cast<const float4*>(X + i + 4);
    s8v o;
    o[0] = (short)f2bf(a.x); o[1] = (short)f2bf(a.y);
    o[2] = (short)f2bf(a.z); o[3] = (short)f2bf(a.w);
    o[4] = (short)f2bf(b.x); o[5] = (short)f2bf(b.y);
    o[6] = (short)f2bf(b.z); o[7] = (short)f2bf(b.w);
    *reinterpret_cast<s8v*>(Y + i) = o;
}

// ---------------------------------------------------------------------------
// Kernel 1: weight convert + transpose.  W[k][n] fp32  ->  Wt[n][k] bf16
// ---------------------------------------------------------------------------
__global__ __launch_bounds__(256) void transpose_cvt_k(
        const float* __restrict__ W0, const float* __restrict__ W1,
        const float* __restrict__ W2, const float* __restrict__ W3,
        unsigned short* __restrict__ T0, unsigned short* __restrict__ T1,
        unsigned short* __restrict__ T2, unsigned short* __restrict__ T3) {
    __shared__ float tile[32][33];
    const float* W; unsigned short* T;
    switch (blockIdx.z) {
        case 0:  W = W0; T = T0; break;
        case 1:  W = W1; T = T1; break;
        case 2:  W = W2; T = T2; break;
        default: W = W3; T = T3; break;
    }
    int tx = threadIdx.x & 31, ty = threadIdx.x >> 5;      // ty: 0..7
    int k0 = blockIdx.x * 32, n0 = blockIdx.y * 32;
#pragma unroll
    for (int i = 0; i < 32; i += 8)
        tile[ty + i][tx] = W[(size_t)(k0 + ty + i) * 1024 + n0 + tx];
    __syncthreads();
#pragma unroll
    for (int i = 0; i < 32; i += 8)
        T[(size_t)(n0 + ty + i) * 1024 + k0 + tx] = f2bf(tile[tx][ty + i]);
}

// ---------------------------------------------------------------------------
// GEMM body (m97 structure): BK=32, linear LDS, global_load_lds w=16.
//   OUT_MODE: 0 = bf16 row-major, 1 = f32 row-major, 2 = bf16 Vt[b][h][d][s]
// ---------------------------------------------------------------------------
template <int OUT_MODE>
__device__ __forceinline__ void gemm_body(
        const unsigned short* __restrict__ A, const unsigned short* __restrict__ Bt,
        const float* __restrict__ bias, void* __restrict__ C,
        unsigned short* As, unsigned short* Bs, int row0, int col0) {
    constexpr int Kd = 1024, Nd = 1024;
    const int tid  = threadIdx.x;
    const int lane = tid & 63, wave = tid >> 6;
    const int g = lane >> 4, li = lane & 15;
    const int wr = wave >> 1, wc = wave & 1;
    const int lrow = lane >> 2, lcol = (lane & 3) * 8;

    f4v acc[4][4];
#pragma unroll
    for (int m = 0; m < 4; m++)
#pragma unroll
        for (int n = 0; n < 4; n++) acc[m][n] = (f4v){0.f, 0.f, 0.f, 0.f};

    for (int kt = 0; kt < Kd; kt += 32) {
        __syncthreads();
#pragma unroll
        for (int jj = 0; jj < 2; jj++) {
            int j = wave * 2 + jj;
            gl16(A  + (size_t)(row0 + j * 16 + lrow) * Kd + kt + lcol, &As[j * 512]);
            gl16(Bt + (size_t)(col0 + j * 16 + lrow) * Kd + kt + lcol, &Bs[j * 512]);
        }
        __syncthreads();

        s8v af[4], bf[4];
#pragma unroll
        for (int m = 0; m < 4; m++)
            af[m] = *reinterpret_cast<const s8v*>(&As[(wr * 64 + m * 16 + li) * 32 + g * 8]);
#pragma unroll
        for (int n = 0; n < 4; n++)
            bf[n] = *reinterpret_cast<const s8v*>(&Bs[(wc * 64 + n * 16 + li) * 32 + g * 8]);
        __builtin_amdgcn_s_setprio(1);
#pragma unroll
        for (int m = 0; m < 4; m++)
#pragma unroll
            for (int n = 0; n < 4; n++)
                acc[m][n] = MFMA16(af[m], bf[n], acc[m][n]);
        __builtin_amdgcn_s_setprio(0);
    }

#pragma unroll
    for (int n = 0; n < 4; n++) {
        int col = col0 + wc * 64 + n * 16 + li;
        float bv = bias[col];
#pragma unroll
        for (int m = 0; m < 4; m++) {
            int rbase = row0 + wr * 64 + m * 16 + g * 4;
            if constexpr (OUT_MODE == 2) {
                int h = col >> 6, d = col & 63;
                int b = rbase >> 11, s = rbase & 2047;
                ushort4 pk;
                pk.x = f2bf(acc[m][n][0] + bv);
                pk.y = f2bf(acc[m][n][1] + bv);
                pk.z = f2bf(acc[m][n][2] + bv);
                pk.w = f2bf(acc[m][n][3] + bv);
                *reinterpret_cast<ushort4*>(
                    (unsigned short*)C + ((((size_t)b * 16 + h) * 64 + d) * 2048 + s)) = pk;
            } else {
#pragma unroll
                for (int r = 0; r < 4; r++) {
                    float v = acc[m][n][r] + bv;
                    if constexpr (OUT_MODE == 1)
                        ((float*)C)[(size_t)(rbase + r) * Nd + col] = v;
                    else
                        ((unsigned short*)C)[(size_t)(rbase + r) * Nd + col] = f2bf(v);
                }
            }
        }
    }
}

// Kernel 2a: fused Q/K/V projection GEMMs (blockIdx.z selects input)
__global__ __launch_bounds__(256, 3) void qkv_gemm_k(
        const unsigned short* __restrict__ Qx, const unsigned short* __restrict__ Kx,
        const unsigned short* __restrict__ Vx,
        const unsigned short* __restrict__ Wqt, const unsigned short* __restrict__ Wkt,
        const unsigned short* __restrict__ Wvt,
        const float* __restrict__ bq, const float* __restrict__ bk,
        const float* __restrict__ bv,
        unsigned short* __restrict__ Qb, unsigned short* __restrict__ Kb,
        unsigned short* __restrict__ Vtb) {
    __shared__ __attribute__((aligned(16))) unsigned short As[128 * 32];
    __shared__ __attribute__((aligned(16))) unsigned short Bs[128 * 32];
    const int row0 = blockIdx.y * 128, col0 = blockIdx.x * 128;
    switch (blockIdx.z) {
        case 0:  gemm_body<0>(Qx, Wqt, bq, Qb,  As, Bs, row0, col0); break;
        case 1:  gemm_body<0>(Kx, Wkt, bk, Kb,  As, Bs, row0, col0); break;
        default: gemm_body<2>(Vx, Wvt, bv, Vtb, As, Bs, row0, col0); break;
    }
}

// Kernel 2b: output projection GEMM (f32 out)
__global__ __launch_bounds__(256, 3) void out_gemm_k(
        const unsigned short* __restrict__ A, const unsigned short* __restrict__ Bt,
        const float* __restrict__ bias, float* __restrict__ C) {
    __shared__ __attribute__((aligned(16))) unsigned short As[128 * 32];
    __shared__ __attribute__((aligned(16))) unsigned short Bs[128 * 32];
    gemm_body<1>(A, Bt, bias, C, As, Bs, blockIdx.y * 128, blockIdx.x * 128);
}

// ---------------------------------------------------------------------------
// Kernel 3: flash attention.  Round-12 champion structure (KVB=128, qt-pair,
//   512 blocks, XCD decode, P-swizzle, setprio) + QK kf-hoist: all 8 K
//   fragments loaded before the 16-MFMA burst (8 ds_reads in flight instead
//   of a 16-deep read->MFMA latency chain).
// ---------------------------------------------------------------------------
__global__ __launch_bounds__(256, 2) void attn_k(
        const unsigned short* __restrict__ Q, const unsigned short* __restrict__ K,
        const unsigned short* __restrict__ Vt, unsigned short* __restrict__ Ctx) {
    constexpr int S = 2048, Dm = 1024, DKh = 64;
    constexpr int LDK = 72, LDV = 136, LDP = 40;
    constexpr float CEXP = 0.125f * 1.44269504f;    // scale * log2(e)
    __shared__ __attribute__((aligned(16))) unsigned short K_lds[128 * LDK];   // [s][d]
    __shared__ __attribute__((aligned(16))) unsigned short V_lds[64 * LDV];    // [d][s]
    __shared__ __attribute__((aligned(16))) unsigned short P_lds[4][32 * LDP]; // per-wave

    const int tid  = threadIdx.x;
    const int lane = tid & 63, wave = tid >> 6;
    const int g = lane >> 4, li = lane & 15;
    // XCD-grouped bijective decode: bits [0:2]=xcd, [3:5]=sub-head, [6:8]=q-pair
    const int id = blockIdx.x;
    const int bh = (id & 7) * 8 + ((id >> 3) & 7);
    const int qp = id >> 6;                          // 0..7, covers 256 q rows
    const int b = bh >> 4, h = bh & 15;
    const size_t base  = (size_t)b * S * Dm + (size_t)h * DKh;   // [b,s,h,d]
    const size_t vbase = (size_t)bh * DKh * S;                   // [b,h,d,s]
    const int q00 = qp * 256 + wave * 32;            // qt=0 base; qt=1 adds 128

    // Q fragments hoisted to registers (both q-tiles)
    s8v qf[2][2][2];
#pragma unroll
    for (int qt = 0; qt < 2; qt++)
#pragma unroll
        for (int rb = 0; rb < 2; rb++)
#pragma unroll
            for (int ks = 0; ks < 2; ks++)
                qf[qt][rb][ks] = *reinterpret_cast<const s8v*>(
                        Q + base + (size_t)(q00 + qt * 128 + rb * 16 + li) * Dm
                           + ks * 32 + g * 8);

    f4v octx[2][2][4];
    float m_run[2][2][4], l_run[2][2][4];
#pragma unroll
    for (int qt = 0; qt < 2; qt++)
#pragma unroll
        for (int rb = 0; rb < 2; rb++) {
#pragma unroll
            for (int nb = 0; nb < 4; nb++) octx[qt][rb][nb] = (f4v){0.f, 0.f, 0.f, 0.f};
#pragma unroll
            for (int r = 0; r < 4; r++) { m_run[qt][rb][r] = -1e30f; l_run[qt][rb][r] = 0.f; }
        }

    const int rdswz = ((li >> 2) & 3) << 3;          // P_lds read-side XOR key

    for (int t = 0; t < 16; t++) {
        const int kv0 = t * 128;
        __syncthreads();   // protect prev-tile LDS reads
        // ---- stage K [128 s][64 d] and V [64 d][128 s], both vectorized ----
#pragma unroll
        for (int i = 0; i < 4; i++) {
            int e = (i * 256 + tid) * 8;
            int s = e >> 6, d = e & 63;
            *reinterpret_cast<s8v*>(&K_lds[s * LDK + d]) =
                *reinterpret_cast<const s8v*>(K + base + (size_t)(kv0 + s) * Dm + d);
            int dv = e >> 7, sv = e & 127;
            *reinterpret_cast<s8v*>(&V_lds[dv * LDV + sv]) =
                *reinterpret_cast<const s8v*>(Vt + vbase + (size_t)dv * S + kv0 + sv);
        }
        __syncthreads();

#pragma unroll
        for (int qt = 0; qt < 2; qt++) {
            // ---- scores: S = Q @ K^T  (kf fragments hoisted per ks) ----
            f4v sc[2][8];
#pragma unroll
            for (int rb = 0; rb < 2; rb++)
#pragma unroll
                for (int cb = 0; cb < 8; cb++) sc[rb][cb] = (f4v){0.f, 0.f, 0.f, 0.f};
            __builtin_amdgcn_s_setprio(1);
#pragma unroll
            for (int ks = 0; ks < 2; ks++) {
                s8v kf[8];
#pragma unroll
                for (int cb = 0; cb < 8; cb++)
                    kf[cb] = *reinterpret_cast<const s8v*>(
                            &K_lds[(cb * 16 + li) * LDK + ks * 32 + g * 8]);
#pragma unroll
                for (int cb = 0; cb < 8; cb++) {
                    sc[0][cb] = MFMA16(qf[qt][0][ks], kf[cb], sc[0][cb]);
                    sc[1][cb] = MFMA16(qf[qt][1][ks], kf[cb], sc[1][cb]);
                }
            }
            __builtin_amdgcn_s_setprio(0);

            // ---- online softmax (exp2 domain) ----
            float rsum[2][4];
#pragma unroll
            for (int rb = 0; rb < 2; rb++) {
                float rmax[4];
#pragma unroll
                for (int r = 0; r < 4; r++) {
                    float v01 = fmaxf(sc[rb][0][r], sc[rb][1][r]);
                    float v23 = fmaxf(sc[rb][2][r], sc[rb][3][r]);
                    float v45 = fmaxf(sc[rb][4][r], sc[rb][5][r]);
                    float v67 = fmaxf(sc[rb][6][r], sc[rb][7][r]);
                    rmax[r] = fmaxf(fmaxf(v01, v23), fmaxf(v45, v67)) * CEXP;
                }
#pragma unroll
                for (int mask = 1; mask < 16; mask <<= 1)
#pragma unroll
                    for (int r = 0; r < 4; r++)
                        rmax[r] = fmaxf(rmax[r], __shfl_xor(rmax[r], mask, 64));
#pragma unroll
                for (int r = 0; r < 4; r++) {
                    float mn = fmaxf(m_run[qt][rb][r], rmax[r]);
                    float scl = __builtin_amdgcn_exp2f(m_run[qt][rb][r] - mn);
                    m_run[qt][rb][r] = mn;
                    l_run[qt][rb][r] *= scl;
                    rsum[rb][r] = 0.f;
#pragma unroll
                    for (int nb = 0; nb < 4; nb++) octx[qt][rb][nb][r] *= scl;
                }
            }

            // ---- P chunks (32 kv cols) interleaved with PV MFMA ----
#pragma unroll
            for (int ks = 0; ks < 4; ks++) {
#pragma unroll
                for (int rb = 0; rb < 2; rb++) {
#pragma unroll
                    for (int cc = 0; cc < 2; cc++) {
                        int cb = ks * 2 + cc;
                        float p0 = __builtin_amdgcn_exp2f(fmaf(sc[rb][cb][0], CEXP, -m_run[qt][rb][0]));
                        float p1 = __builtin_amdgcn_exp2f(fmaf(sc[rb][cb][1], CEXP, -m_run[qt][rb][1]));
                        float p2 = __builtin_amdgcn_exp2f(fmaf(sc[rb][cb][2], CEXP, -m_run[qt][rb][2]));
                        float p3 = __builtin_amdgcn_exp2f(fmaf(sc[rb][cb][3], CEXP, -m_run[qt][rb][3]));
                        rsum[rb][0] += p0; rsum[rb][1] += p1;
                        rsum[rb][2] += p2; rsum[rb][3] += p3;
                        unsigned int u01 = cvt_pk_bf16(p0, p1);
                        unsigned int u23 = cvt_pk_bf16(p2, p3);
                        int rowb = rb * 16 + g * 4;
                        int colS = (cc * 16 + li) ^ (g << 3);   // write-side swizzle
                        P_lds[wave][(rowb + 0) * LDP + colS] = (unsigned short)u01;
                        P_lds[wave][(rowb + 1) * LDP + colS] = (unsigned short)(u01 >> 16);
                        P_lds[wave][(rowb + 2) * LDP + colS] = (unsigned short)u23;
                        P_lds[wave][(rowb + 3) * LDP + colS] = (unsigned short)(u23 >> 16);
                    }
                }
                s8v vf[4], pf[2];
#pragma unroll
                for (int nb = 0; nb < 4; nb++)
                    vf[nb] = *reinterpret_cast<const s8v*>(
                            &V_lds[(nb * 16 + li) * LDV + ks * 32 + g * 8]);
#pragma unroll
                for (int rb = 0; rb < 2; rb++)
                    pf[rb] = *reinterpret_cast<const s8v*>(
                            &P_lds[wave][(rb * 16 + li) * LDP + ((g * 8) ^ rdswz)]);
                __builtin_amdgcn_s_setprio(1);
#pragma unroll
                for (int rb = 0; rb < 2; rb++)
#pragma unroll
                    for (int nb = 0; nb < 4; nb++)
                        octx[qt][rb][nb] = MFMA16(pf[rb], vf[nb], octx[qt][rb][nb]);
                __builtin_amdgcn_s_setprio(0);
            }

            // ---- fold tile sums into running denominators ----
#pragma unroll
            for (int mask = 1; mask < 16; mask <<= 1)
#pragma unroll
                for (int rb = 0; rb < 2; rb++)
#pragma unroll
                    for (int r = 0; r < 4; r++)
                        rsum[rb][r] += __shfl_xor(rsum[rb][r], mask, 64);
#pragma unroll
            for (int rb = 0; rb < 2; rb++)
#pragma unroll
                for (int r = 0; r < 4; r++) l_run[qt][rb][r] += rsum[rb][r];
        }
    }

    // ---- epilogue: normalize, write bf16 ctx in [b,s,h*64+d] layout ----
#pragma unroll
    for (int qt = 0; qt < 2; qt++)
#pragma unroll
        for (int rb = 0; rb < 2; rb++)
#pragma unroll
            for (int r = 0; r < 4; r++) {
                float inv = 1.0f / l_run[qt][rb][r];
                int row = q00 + qt * 128 + rb * 16 + g * 4 + r;
#pragma unroll
                for (int nb = 0; nb < 4; nb++) {
                    int d = nb * 16 + li;
                    Ctx[base + (size_t)row * Dm + d] = f2bf(octx[qt][rb][nb][r] * inv);
                }
            }
}

// ---------------------------------------------------------------------------
extern "C" void kernel_launch(void* const* d_in, const int* in_sizes, int n_in,
                              void* d_out, int out_size, void* d_ws, size_t ws_size,
                              hipStream_t stream) {
    const float* query = (const float*)d_in[0];
    const float* key   = (const float*)d_in[1];
    const float* value = (const float*)d_in[2];
    const float* Wq = (const float*)d_in[3];
    const float* bq = (const float*)d_in[4];
    const float* Wk = (const float*)d_in[5];
    const float* bk = (const float*)d_in[6];
    const float* Wv = (const float*)d_in[7];
    const float* bv = (const float*)d_in[8];
    const float* Wo = (const float*)d_in[9];
    const float* bo = (const float*)d_in[10];

    unsigned short* ws = (unsigned short*)d_ws;
    const size_t MD = (size_t)8192 * 1024;
    unsigned short* Qb  = ws;
    unsigned short* Kb  = Qb + MD;
    unsigned short* Vtb = Kb + MD;   // Vt[b][h][d][s]
    unsigned short* Cb  = Vtb + MD;
    unsigned short* Qx  = Cb + MD;   // bf16 activations
    unsigned short* Kx  = Qx + MD;
    unsigned short* Vx  = Kx + MD;
    unsigned short* Wqt = Vx + MD;
    unsigned short* Wkt = Wqt + 1024 * 1024;
    unsigned short* Wvt = Wkt + 1024 * 1024;
    unsigned short* Wot = Wvt + 1024 * 1024;

    cvt_bf16_k<<<dim3(4096, 3), 256, 0, stream>>>(query, key, value, Qx, Kx, Vx);
    transpose_cvt_k<<<dim3(32, 32, 4), 256, 0, stream>>>(Wq, Wk, Wv, Wo, Wqt, Wkt, Wvt, Wot);
    qkv_gemm_k<<<dim3(8, 64, 3), 256, 0, stream>>>(Qx, Kx, Vx, Wqt, Wkt, Wvt,
                                                   bq, bk, bv, Qb, Kb, Vtb);
    attn_k<<<512, 256, 0, stream>>>(Qb, Kb, Vtb, Cb);
    out_gemm_k<<<dim3(8, 64), 256, 0, stream>>>(Cb, Wot, bo, (float*)d_out);
}

// Round 18
// 285.801 us; speedup vs baseline: 1.0353x; 1.0353x over previous
//
#include <hip/hip_runtime.h>

typedef __attribute__((ext_vector_type(8))) short s8v;     // 8 x bf16 bits
typedef __attribute__((ext_vector_type(4))) float f4v;     // 4 x f32

#define MFMA16(a, b, c) __builtin_amdgcn_mfma_f32_16x16x32_bf16(a, b, c, 0, 0, 0)

__device__ __forceinline__ unsigned short f2bf(float f) {
    union { float f; unsigned int u; } v; v.f = f;
    unsigned int u = v.u;
    unsigned int r = (u + 0x7FFFu + ((u >> 16) & 1u)) >> 16;  // RNE
    return (unsigned short)r;
}

__device__ __forceinline__ unsigned int cvt_pk_bf16(float lo, float hi) {
    unsigned int r;
    asm volatile("v_cvt_pk_bf16_f32 %0, %1, %2" : "=v"(r) : "v"(lo), "v"(hi));
    return r;
}

// global -> LDS async copy, 16B per lane; LDS dest = wave-uniform base + lane*16
__device__ __forceinline__ void gl16(const void* g, void* l) {
    __builtin_amdgcn_global_load_lds(
        (const __attribute__((address_space(1))) void*)g,
        (__attribute__((address_space(3))) void*)l, 16, 0, 0);
}

// ---------------------------------------------------------------------------
// Kernel 0: fused prep — activation fp32->bf16 convert (blocks 0..12287) and
//   weight convert+transpose (blocks 12288..16383).  Transpose hides under
//   the BW-bound cvt; saves one dispatch gap.
// ---------------------------------------------------------------------------
__global__ __launch_bounds__(256) void prep_k(
        const float* __restrict__ X0, const float* __restrict__ X1,
        const float* __restrict__ X2,
        unsigned short* __restrict__ Y0, unsigned short* __restrict__ Y1,
        unsigned short* __restrict__ Y2,
        const float* __restrict__ W0, const float* __restrict__ W1,
        const float* __restrict__ W2, const float* __restrict__ W3,
        unsigned short* __restrict__ T0, unsigned short* __restrict__ T1,
        unsigned short* __restrict__ T2, unsigned short* __restrict__ T3) {
    __shared__ float tile[32][33];
    const int id = blockIdx.x;
    if (id < 12288) {
        const float* X; unsigned short* Y;
        switch (id >> 12) {
            case 0:  X = X0; Y = Y0; break;
            case 1:  X = X1; Y = Y1; break;
            default: X = X2; Y = Y2; break;
        }
        size_t i = ((size_t)(id & 4095) * 256 + threadIdx.x) * 8;
        float4 a = *reinterpret_cast<const float4*>(X + i);
        float4 b = *reinterpret_cast<const float4*>(X + i + 4);
        s8v o;
        o[0] = (short)f2bf(a.x); o[1] = (short)f2bf(a.y);
        o[2] = (short)f2bf(a.z); o[3] = (short)f2bf(a.w);
        o[4] = (short)f2bf(b.x); o[5] = (short)f2bf(b.y);
        o[6] = (short)f2bf(b.z); o[7] = (short)f2bf(b.w);
        *reinterpret_cast<s8v*>(Y + i) = o;
    } else {
        const int t = id - 12288;              // 0..4095
        const float* W; unsigned short* T;
        switch (t >> 10) {
            case 0:  W = W0; T = T0; break;
            case 1:  W = W1; T = T1; break;
            case 2:  W = W2; T = T2; break;
            default: W = W3; T = T3; break;
        }
        const int rem = t & 1023;
        const int k0 = (rem & 31) * 32, n0 = (rem >> 5) * 32;
        int tx = threadIdx.x & 31, ty = threadIdx.x >> 5;  // ty: 0..7
#pragma unroll
        for (int i = 0; i < 32; i += 8)
            tile[ty + i][tx] = W[(size_t)(k0 + ty + i) * 1024 + n0 + tx];
        __syncthreads();
#pragma unroll
        for (int i = 0; i < 32; i += 8)
            T[(size_t)(n0 + ty + i) * 1024 + k0 + tx] = f2bf(tile[tx][ty + i]);
    }
}

// ---------------------------------------------------------------------------
// GEMM body (m97 structure): BK=32, linear LDS, global_load_lds w=16.
//   OUT_MODE: 0 = bf16 row-major, 1 = f32 row-major, 2 = bf16 Vt[b][h][d][s]
// ---------------------------------------------------------------------------
template <int OUT_MODE>
__device__ __forceinline__ void gemm_body(
        const unsigned short* __restrict__ A, const unsigned short* __restrict__ Bt,
        const float* __restrict__ bias, void* __restrict__ C,
        unsigned short* As, unsigned short* Bs, int row0, int col0) {
    constexpr int Kd = 1024, Nd = 1024;
    const int tid  = threadIdx.x;
    const int lane = tid & 63, wave = tid >> 6;
    const int g = lane >> 4, li = lane & 15;
    const int wr = wave >> 1, wc = wave & 1;
    const int lrow = lane >> 2, lcol = (lane & 3) * 8;

    f4v acc[4][4];
#pragma unroll
    for (int m = 0; m < 4; m++)
#pragma unroll
        for (int n = 0; n < 4; n++) acc[m][n] = (f4v){0.f, 0.f, 0.f, 0.f};

    for (int kt = 0; kt < Kd; kt += 32) {
        __syncthreads();
#pragma unroll
        for (int jj = 0; jj < 2; jj++) {
            int j = wave * 2 + jj;
            gl16(A  + (size_t)(row0 + j * 16 + lrow) * Kd + kt + lcol, &As[j * 512]);
            gl16(Bt + (size_t)(col0 + j * 16 + lrow) * Kd + kt + lcol, &Bs[j * 512]);
        }
        __syncthreads();

        s8v af[4], bf[4];
#pragma unroll
        for (int m = 0; m < 4; m++)
            af[m] = *reinterpret_cast<const s8v*>(&As[(wr * 64 + m * 16 + li) * 32 + g * 8]);
#pragma unroll
        for (int n = 0; n < 4; n++)
            bf[n] = *reinterpret_cast<const s8v*>(&Bs[(wc * 64 + n * 16 + li) * 32 + g * 8]);
        __builtin_amdgcn_s_setprio(1);
#pragma unroll
        for (int m = 0; m < 4; m++)
#pragma unroll
            for (int n = 0; n < 4; n++)
                acc[m][n] = MFMA16(af[m], bf[n], acc[m][n]);
        __builtin_amdgcn_s_setprio(0);
    }

#pragma unroll
    for (int n = 0; n < 4; n++) {
        int col = col0 + wc * 64 + n * 16 + li;
        float bv = bias[col];
#pragma unroll
        for (int m = 0; m < 4; m++) {
            int rbase = row0 + wr * 64 + m * 16 + g * 4;
            if constexpr (OUT_MODE == 2) {
                int h = col >> 6, d = col & 63;
                int b = rbase >> 11, s = rbase & 2047;
                ushort4 pk;
                pk.x = f2bf(acc[m][n][0] + bv);
                pk.y = f2bf(acc[m][n][1] + bv);
                pk.z = f2bf(acc[m][n][2] + bv);
                pk.w = f2bf(acc[m][n][3] + bv);
                *reinterpret_cast<ushort4*>(
                    (unsigned short*)C + ((((size_t)b * 16 + h) * 64 + d) * 2048 + s)) = pk;
            } else {
#pragma unroll
                for (int r = 0; r < 4; r++) {
                    float v = acc[m][n][r] + bv;
                    if constexpr (OUT_MODE == 1)
                        ((float*)C)[(size_t)(rbase + r) * Nd + col] = v;
                    else
                        ((unsigned short*)C)[(size_t)(rbase + r) * Nd + col] = f2bf(v);
                }
            }
        }
    }
}

// Kernel 2a: fused Q/K/V projection GEMMs (blockIdx.z selects input)
__global__ __launch_bounds__(256, 3) void qkv_gemm_k(
        const unsigned short* __restrict__ Qx, const unsigned short* __restrict__ Kx,
        const unsigned short* __restrict__ Vx,
        const unsigned short* __restrict__ Wqt, const unsigned short* __restrict__ Wkt,
        const unsigned short* __restrict__ Wvt,
        const float* __restrict__ bq, const float* __restrict__ bk,
        const float* __restrict__ bv,
        unsigned short* __restrict__ Qb, unsigned short* __restrict__ Kb,
        unsigned short* __restrict__ Vtb) {
    __shared__ __attribute__((aligned(16))) unsigned short As[128 * 32];
    __shared__ __attribute__((aligned(16))) unsigned short Bs[128 * 32];
    const int row0 = blockIdx.y * 128, col0 = blockIdx.x * 128;
    switch (blockIdx.z) {
        case 0:  gemm_body<0>(Qx, Wqt, bq, Qb,  As, Bs, row0, col0); break;
        case 1:  gemm_body<0>(Kx, Wkt, bk, Kb,  As, Bs, row0, col0); break;
        default: gemm_body<2>(Vx, Wvt, bv, Vtb, As, Bs, row0, col0); break;
    }
}

// Kernel 2b: output projection GEMM (f32 out)
__global__ __launch_bounds__(256, 3) void out_gemm_k(
        const unsigned short* __restrict__ A, const unsigned short* __restrict__ Bt,
        const float* __restrict__ bias, float* __restrict__ C) {
    __shared__ __attribute__((aligned(16))) unsigned short As[128 * 32];
    __shared__ __attribute__((aligned(16))) unsigned short Bs[128 * 32];
    gemm_body<1>(A, Bt, bias, C, As, Bs, blockIdx.y * 128, blockIdx.x * 128);
}

// ---------------------------------------------------------------------------
// Kernel 3: flash attention.  Round-12 champion, FROZEN VERBATIM: KVB=128,
//   qt-pair, 512 blocks, XCD decode, P-swizzle, setprio, per-tile rsum reduce.
// ---------------------------------------------------------------------------
__global__ __launch_bounds__(256, 2) void attn_k(
        const unsigned short* __restrict__ Q, const unsigned short* __restrict__ K,
        const unsigned short* __restrict__ Vt, unsigned short* __restrict__ Ctx) {
    constexpr int S = 2048, Dm = 1024, DKh = 64;
    constexpr int LDK = 72, LDV = 136, LDP = 40;
    constexpr float CEXP = 0.125f * 1.44269504f;    // scale * log2(e)
    __shared__ __attribute__((aligned(16))) unsigned short K_lds[128 * LDK];   // [s][d]
    __shared__ __attribute__((aligned(16))) unsigned short V_lds[64 * LDV];    // [d][s]
    __shared__ __attribute__((aligned(16))) unsigned short P_lds[4][32 * LDP]; // per-wave

    const int tid  = threadIdx.x;
    const int lane = tid & 63, wave = tid >> 6;
    const int g = lane >> 4, li = lane & 15;
    // XCD-grouped bijective decode: bits [0:2]=xcd, [3:5]=sub-head, [6:8]=q-pair
    const int id = blockIdx.x;
    const int bh = (id & 7) * 8 + ((id >> 3) & 7);
    const int qp = id >> 6;                          // 0..7, covers 256 q rows
    const int b = bh >> 4, h = bh & 15;
    const size_t base  = (size_t)b * S * Dm + (size_t)h * DKh;   // [b,s,h,d]
    const size_t vbase = (size_t)bh * DKh * S;                   // [b,h,d,s]
    const int q00 = qp * 256 + wave * 32;            // qt=0 base; qt=1 adds 128

    // Q fragments hoisted to registers (both q-tiles)
    s8v qf[2][2][2];
#pragma unroll
    for (int qt = 0; qt < 2; qt++)
#pragma unroll
        for (int rb = 0; rb < 2; rb++)
#pragma unroll
            for (int ks = 0; ks < 2; ks++)
                qf[qt][rb][ks] = *reinterpret_cast<const s8v*>(
                        Q + base + (size_t)(q00 + qt * 128 + rb * 16 + li) * Dm
                           + ks * 32 + g * 8);

    f4v octx[2][2][4];
    float m_run[2][2][4], l_run[2][2][4];
#pragma unroll
    for (int qt = 0; qt < 2; qt++)
#pragma unroll
        for (int rb = 0; rb < 2; rb++) {
#pragma unroll
            for (int nb = 0; nb < 4; nb++) octx[qt][rb][nb] = (f4v){0.f, 0.f, 0.f, 0.f};
#pragma unroll
            for (int r = 0; r < 4; r++) { m_run[qt][rb][r] = -1e30f; l_run[qt][rb][r] = 0.f; }
        }

    const int rdswz = ((li >> 2) & 3) << 3;          // P_lds read-side XOR key

    for (int t = 0; t < 16; t++) {
        const int kv0 = t * 128;
        __syncthreads();   // protect prev-tile LDS reads
        // ---- stage K [128 s][64 d] and V [64 d][128 s], both vectorized ----
#pragma unroll
        for (int i = 0; i < 4; i++) {
            int e = (i * 256 + tid) * 8;
            int s = e >> 6, d = e & 63;
            *reinterpret_cast<s8v*>(&K_lds[s * LDK + d]) =
                *reinterpret_cast<const s8v*>(K + base + (size_t)(kv0 + s) * Dm + d);
            int dv = e >> 7, sv = e & 127;
            *reinterpret_cast<s8v*>(&V_lds[dv * LDV + sv]) =
                *reinterpret_cast<const s8v*>(Vt + vbase + (size_t)dv * S + kv0 + sv);
        }
        __syncthreads();

#pragma unroll
        for (int qt = 0; qt < 2; qt++) {
            // ---- scores: S = Q @ K^T ----
            f4v sc[2][8];
#pragma unroll
            for (int rb = 0; rb < 2; rb++)
#pragma unroll
                for (int cb = 0; cb < 8; cb++) sc[rb][cb] = (f4v){0.f, 0.f, 0.f, 0.f};
            __builtin_amdgcn_s_setprio(1);
#pragma unroll
            for (int cb = 0; cb < 8; cb++) {
#pragma unroll
                for (int ks = 0; ks < 2; ks++) {
                    s8v kf = *reinterpret_cast<const s8v*>(
                            &K_lds[(cb * 16 + li) * LDK + ks * 32 + g * 8]);
                    sc[0][cb] = MFMA16(qf[qt][0][ks], kf, sc[0][cb]);
                    sc[1][cb] = MFMA16(qf[qt][1][ks], kf, sc[1][cb]);
                }
            }
            __builtin_amdgcn_s_setprio(0);

            // ---- online softmax (exp2 domain) ----
            float rsum[2][4];
#pragma unroll
            for (int rb = 0; rb < 2; rb++) {
                float rmax[4];
#pragma unroll
                for (int r = 0; r < 4; r++) {
                    float v = sc[rb][0][r];
#pragma unroll
                    for (int cb = 1; cb < 8; cb++) v = fmaxf(v, sc[rb][cb][r]);
                    rmax[r] = v * CEXP;
                }
#pragma unroll
                for (int mask = 1; mask < 16; mask <<= 1)
#pragma unroll
                    for (int r = 0; r < 4; r++)
                        rmax[r] = fmaxf(rmax[r], __shfl_xor(rmax[r], mask, 64));
#pragma unroll
                for (int r = 0; r < 4; r++) {
                    float mn = fmaxf(m_run[qt][rb][r], rmax[r]);
                    float scl = __builtin_amdgcn_exp2f(m_run[qt][rb][r] - mn);
                    m_run[qt][rb][r] = mn;
                    l_run[qt][rb][r] *= scl;
                    rsum[rb][r] = 0.f;
#pragma unroll
                    for (int nb = 0; nb < 4; nb++) octx[qt][rb][nb][r] *= scl;
                }
            }

            // ---- P chunks (32 kv cols) interleaved with PV MFMA ----
#pragma unroll
            for (int ks = 0; ks < 4; ks++) {
#pragma unroll
                for (int rb = 0; rb < 2; rb++) {
#pragma unroll
                    for (int cc = 0; cc < 2; cc++) {
                        int cb = ks * 2 + cc;
                        float p0 = __builtin_amdgcn_exp2f(fmaf(sc[rb][cb][0], CEXP, -m_run[qt][rb][0]));
                        float p1 = __builtin_amdgcn_exp2f(fmaf(sc[rb][cb][1], CEXP, -m_run[qt][rb][1]));
                        float p2 = __builtin_amdgcn_exp2f(fmaf(sc[rb][cb][2], CEXP, -m_run[qt][rb][2]));
                        float p3 = __builtin_amdgcn_exp2f(fmaf(sc[rb][cb][3], CEXP, -m_run[qt][rb][3]));
                        rsum[rb][0] += p0; rsum[rb][1] += p1;
                        rsum[rb][2] += p2; rsum[rb][3] += p3;
                        unsigned int u01 = cvt_pk_bf16(p0, p1);
                        unsigned int u23 = cvt_pk_bf16(p2, p3);
                        int rowb = rb * 16 + g * 4;
                        int colS = (cc * 16 + li) ^ (g << 3);   // write-side swizzle
                        P_lds[wave][(rowb + 0) * LDP + colS] = (unsigned short)u01;
                        P_lds[wave][(rowb + 1) * LDP + colS] = (unsigned short)(u01 >> 16);
                        P_lds[wave][(rowb + 2) * LDP + colS] = (unsigned short)u23;
                        P_lds[wave][(rowb + 3) * LDP + colS] = (unsigned short)(u23 >> 16);
                    }
                }
                s8v vf[4], pf[2];
#pragma unroll
                for (int nb = 0; nb < 4; nb++)
                    vf[nb] = *reinterpret_cast<const s8v*>(
                            &V_lds[(nb * 16 + li) * LDV + ks * 32 + g * 8]);
#pragma unroll
                for (int rb = 0; rb < 2; rb++)
                    pf[rb] = *reinterpret_cast<const s8v*>(
                            &P_lds[wave][(rb * 16 + li) * LDP + ((g * 8) ^ rdswz)]);
                __builtin_amdgcn_s_setprio(1);
#pragma unroll
                for (int rb = 0; rb < 2; rb++)
#pragma unroll
                    for (int nb = 0; nb < 4; nb++)
                        octx[qt][rb][nb] = MFMA16(pf[rb], vf[nb], octx[qt][rb][nb]);
                __builtin_amdgcn_s_setprio(0);
            }

            // ---- fold tile sums into running denominators ----
#pragma unroll
            for (int mask = 1; mask < 16; mask <<= 1)
#pragma unroll
                for (int rb = 0; rb < 2; rb++)
#pragma unroll
                    for (int r = 0; r < 4; r++)
                        rsum[rb][r] += __shfl_xor(rsum[rb][r], mask, 64);
#pragma unroll
            for (int rb = 0; rb < 2; rb++)
#pragma unroll
                for (int r = 0; r < 4; r++) l_run[qt][rb][r] += rsum[rb][r];
        }
    }

    // ---- epilogue: normalize, write bf16 ctx in [b,s,h*64+d] layout ----
#pragma unroll
    for (int qt = 0; qt < 2; qt++)
#pragma unroll
        for (int rb = 0; rb < 2; rb++)
#pragma unroll
            for (int r = 0; r < 4; r++) {
                float inv = 1.0f / l_run[qt][rb][r];
                int row = q00 + qt * 128 + rb * 16 + g * 4 + r;
#pragma unroll
                for (int nb = 0; nb < 4; nb++) {
                    int d = nb * 16 + li;
                    Ctx[base + (size_t)row * Dm + d] = f2bf(octx[qt][rb][nb][r] * inv);
                }
            }
}

// ---------------------------------------------------------------------------
extern "C" void kernel_launch(void* const* d_in, const int* in_sizes, int n_in,
                              void* d_out, int out_size, void* d_ws, size_t ws_size,
                              hipStream_t stream) {
    const float* query = (const float*)d_in[0];
    const float* key   = (const float*)d_in[1];
    const float* value = (const float*)d_in[2];
    const float* Wq = (const float*)d_in[3];
    const float* bq = (const float*)d_in[4];
    const float* Wk = (const float*)d_in[5];
    const float* bk = (const float*)d_in[6];
    const float* Wv = (const float*)d_in[7];
    const float* bv = (const float*)d_in[8];
    const float* Wo = (const float*)d_in[9];
    const float* bo = (const float*)d_in[10];

    unsigned short* ws = (unsigned short*)d_ws;
    const size_t MD = (size_t)8192 * 1024;
    unsigned short* Qb  = ws;
    unsigned short* Kb  = Qb + MD;
    unsigned short* Vtb = Kb + MD;   // Vt[b][h][d][s]
    unsigned short* Cb  = Vtb + MD;
    unsigned short* Qx  = Cb + MD;   // bf16 activations
    unsigned short* Kx  = Qx + MD;
    unsigned short* Vx  = Kx + MD;
    unsigned short* Wqt = Vx + MD;
    unsigned short* Wkt = Wqt + 1024 * 1024;
    unsigned short* Wvt = Wkt + 1024 * 1024;
    unsigned short* Wot = Wvt + 1024 * 1024;

    prep_k<<<16384, 256, 0, stream>>>(query, key, value, Qx, Kx, Vx,
                                      Wq, Wk, Wv, Wo, Wqt, Wkt, Wvt, Wot);
    qkv_gemm_k<<<dim3(8, 64, 3), 256, 0, stream>>>(Qx, Kx, Vx, Wqt, Wkt, Wvt,
                                                   bq, bk, bv, Qb, Kb, Vtb);
    attn_k<<<512, 256, 0, stream>>>(Qb, Kb, Vtb, Cb);
    out_gemm_k<<<dim3(8, 64), 256, 0, stream>>>(Cb, Wot, bo, (float*)d_out);
}

// Round 20
// 284.649 us; speedup vs baseline: 1.0395x; 1.0040x over previous
//
#include <hip/hip_runtime.h>

typedef __attribute__((ext_vector_type(8))) short s8v;     // 8 x bf16 bits
typedef __attribute__((ext_vector_type(4))) float f4v;     // 4 x f32

#define MFMA16(a, b, c) __builtin_amdgcn_mfma_f32_16x16x32_bf16(a, b, c, 0, 0, 0)

__device__ __forceinline__ unsigned short f2bf(float f) {
    union { float f; unsigned int u; } v; v.f = f;
    unsigned int u = v.u;
    unsigned int r = (u + 0x7FFFu + ((u >> 16) & 1u)) >> 16;  // RNE
    return (unsigned short)r;
}

__device__ __forceinline__ unsigned int cvt_pk_bf16(float lo, float hi) {
    unsigned int r;
    asm volatile("v_cvt_pk_bf16_f32 %0, %1, %2" : "=v"(r) : "v"(lo), "v"(hi));
    return r;
}

// global -> LDS async copy, 16B per lane; LDS dest = wave-uniform base + lane*16
__device__ __forceinline__ void gl16(const void* g, void* l) {
    __builtin_amdgcn_global_load_lds(
        (const __attribute__((address_space(1))) void*)g,
        (__attribute__((address_space(3))) void*)l, 16, 0, 0);
}

// ---------------------------------------------------------------------------
// Kernel 0: fused prep — activation fp32->bf16 convert (blocks 0..12287) and
//   weight convert+transpose (blocks 12288..16383).
// ---------------------------------------------------------------------------
__global__ __launch_bounds__(256) void prep_k(
        const float* __restrict__ X0, const float* __restrict__ X1,
        const float* __restrict__ X2,
        unsigned short* __restrict__ Y0, unsigned short* __restrict__ Y1,
        unsigned short* __restrict__ Y2,
        const float* __restrict__ W0, const float* __restrict__ W1,
        const float* __restrict__ W2, const float* __restrict__ W3,
        unsigned short* __restrict__ T0, unsigned short* __restrict__ T1,
        unsigned short* __restrict__ T2, unsigned short* __restrict__ T3) {
    __shared__ float tile[32][33];
    const int id = blockIdx.x;
    if (id < 12288) {
        const float* X; unsigned short* Y;
        switch (id >> 12) {
            case 0:  X = X0; Y = Y0; break;
            case 1:  X = X1; Y = Y1; break;
            default: X = X2; Y = Y2; break;
        }
        size_t i = ((size_t)(id & 4095) * 256 + threadIdx.x) * 8;
        float4 a = *reinterpret_cast<const float4*>(X + i);
        float4 b = *reinterpret_cast<const float4*>(X + i + 4);
        s8v o;
        o[0] = (short)f2bf(a.x); o[1] = (short)f2bf(a.y);
        o[2] = (short)f2bf(a.z); o[3] = (short)f2bf(a.w);
        o[4] = (short)f2bf(b.x); o[5] = (short)f2bf(b.y);
        o[6] = (short)f2bf(b.z); o[7] = (short)f2bf(b.w);
        *reinterpret_cast<s8v*>(Y + i) = o;
    } else {
        const int t = id - 12288;              // 0..4095
        const float* W; unsigned short* T;
        switch (t >> 10) {
            case 0:  W = W0; T = T0; break;
            case 1:  W = W1; T = T1; break;
            case 2:  W = W2; T = T2; break;
            default: W = W3; T = T3; break;
        }
        const int rem = t & 1023;
        const int k0 = (rem & 31) * 32, n0 = (rem >> 5) * 32;
        int tx = threadIdx.x & 31, ty = threadIdx.x >> 5;  // ty: 0..7
#pragma unroll
        for (int i = 0; i < 32; i += 8)
            tile[ty + i][tx] = W[(size_t)(k0 + ty + i) * 1024 + n0 + tx];
        __syncthreads();
#pragma unroll
        for (int i = 0; i < 32; i += 8)
            T[(size_t)(n0 + ty + i) * 1024 + k0 + tx] = f2bf(tile[tx][ty + i]);
    }
}

// ---------------------------------------------------------------------------
// GEMM body (m97 structure): BK=32, linear LDS, global_load_lds w=16.
//   OUT_MODE: 0 = bf16 row-major, 1 = f32 row-major, 2 = bf16 Vt[b][h][d][s]
// ---------------------------------------------------------------------------
template <int OUT_MODE>
__device__ __forceinline__ void gemm_body(
        const unsigned short* __restrict__ A, const unsigned short* __restrict__ Bt,
        const float* __restrict__ bias, void* __restrict__ C,
        unsigned short* As, unsigned short* Bs, int row0, int col0) {
    constexpr int Kd = 1024, Nd = 1024;
    const int tid  = threadIdx.x;
    const int lane = tid & 63, wave = tid >> 6;
    const int g = lane >> 4, li = lane & 15;
    const int wr = wave >> 1, wc = wave & 1;
    const int lrow = lane >> 2, lcol = (lane & 3) * 8;

    f4v acc[4][4];
#pragma unroll
    for (int m = 0; m < 4; m++)
#pragma unroll
        for (int n = 0; n < 4; n++) acc[m][n] = (f4v){0.f, 0.f, 0.f, 0.f};

    for (int kt = 0; kt < Kd; kt += 32) {
        __syncthreads();
#pragma unroll
        for (int jj = 0; jj < 2; jj++) {
            int j = wave * 2 + jj;
            gl16(A  + (size_t)(row0 + j * 16 + lrow) * Kd + kt + lcol, &As[j * 512]);
            gl16(Bt + (size_t)(col0 + j * 16 + lrow) * Kd + kt + lcol, &Bs[j * 512]);
        }
        __syncthreads();

        s8v af[4], bf[4];
#pragma unroll
        for (int m = 0; m < 4; m++)
            af[m] = *reinterpret_cast<const s8v*>(&As[(wr * 64 + m * 16 + li) * 32 + g * 8]);
#pragma unroll
        for (int n = 0; n < 4; n++)
            bf[n] = *reinterpret_cast<const s8v*>(&Bs[(wc * 64 + n * 16 + li) * 32 + g * 8]);
        __builtin_amdgcn_s_setprio(1);
#pragma unroll
        for (int m = 0; m < 4; m++)
#pragma unroll
            for (int n = 0; n < 4; n++)
                acc[m][n] = MFMA16(af[m], bf[n], acc[m][n]);
        __builtin_amdgcn_s_setprio(0);
    }

#pragma unroll
    for (int n = 0; n < 4; n++) {
        int col = col0 + wc * 64 + n * 16 + li;
        float bv = bias[col];
#pragma unroll
        for (int m = 0; m < 4; m++) {
            int rbase = row0 + wr * 64 + m * 16 + g * 4;
            if constexpr (OUT_MODE == 2) {
                int h = col >> 6, d = col & 63;
                int b = rbase >> 11, s = rbase & 2047;
                ushort4 pk;
                pk.x = f2bf(acc[m][n][0] + bv);
                pk.y = f2bf(acc[m][n][1] + bv);
                pk.z = f2bf(acc[m][n][2] + bv);
                pk.w = f2bf(acc[m][n][3] + bv);
                *reinterpret_cast<ushort4*>(
                    (unsigned short*)C + ((((size_t)b * 16 + h) * 64 + d) * 2048 + s)) = pk;
            } else {
#pragma unroll
                for (int r = 0; r < 4; r++) {
                    float v = acc[m][n][r] + bv;
                    if constexpr (OUT_MODE == 1)
                        ((float*)C)[(size_t)(rbase + r) * Nd + col] = v;
                    else
                        ((unsigned short*)C)[(size_t)(rbase + r) * Nd + col] = f2bf(v);
                }
            }
        }
    }
}

// Kernel 2a: fused Q/K/V projection GEMMs (blockIdx.z selects input)
__global__ __launch_bounds__(256, 3) void qkv_gemm_k(
        const unsigned short* __restrict__ Qx, const unsigned short* __restrict__ Kx,
        const unsigned short* __restrict__ Vx,
        const unsigned short* __restrict__ Wqt, const unsigned short* __restrict__ Wkt,
        const unsigned short* __restrict__ Wvt,
        const float* __restrict__ bq, const float* __restrict__ bk,
        const float* __restrict__ bv,
        unsigned short* __restrict__ Qb, unsigned short* __restrict__ Kb,
        unsigned short* __restrict__ Vtb) {
    __shared__ __attribute__((aligned(16))) unsigned short As[128 * 32];
    __shared__ __attribute__((aligned(16))) unsigned short Bs[128 * 32];
    const int row0 = blockIdx.y * 128, col0 = blockIdx.x * 128;
    switch (blockIdx.z) {
        case 0:  gemm_body<0>(Qx, Wqt, bq, Qb,  As, Bs, row0, col0); break;
        case 1:  gemm_body<0>(Kx, Wkt, bk, Kb,  As, Bs, row0, col0); break;
        default: gemm_body<2>(Vx, Wvt, bv, Vtb, As, Bs, row0, col0); break;
    }
}

// Kernel 2b: output projection GEMM (f32 out)
__global__ __launch_bounds__(256, 3) void out_gemm_k(
        const unsigned short* __restrict__ A, const unsigned short* __restrict__ Bt,
        const float* __restrict__ bias, float* __restrict__ C) {
    __shared__ __attribute__((aligned(16))) unsigned short As[128 * 32];
    __shared__ __attribute__((aligned(16))) unsigned short Bs[128 * 32];
    gemm_body<1>(A, Bt, bias, C, As, Bs, blockIdx.y * 128, blockIdx.x * 128);
}

// ---------------------------------------------------------------------------
// Kernel 3: flash attention.  Round-12 champion, FROZEN VERBATIM: KVB=128,
//   qt-pair, 512 blocks, XCD decode, P-swizzle, setprio, per-tile rsum reduce.
// ---------------------------------------------------------------------------
__global__ __launch_bounds__(256, 2) void attn_k(
        const unsigned short* __restrict__ Q, const unsigned short* __restrict__ K,
        const unsigned short* __restrict__ Vt, unsigned short* __restrict__ Ctx) {
    constexpr int S = 2048, Dm = 1024, DKh = 64;
    constexpr int LDK = 72, LDV = 136, LDP = 40;
    constexpr float CEXP = 0.125f * 1.44269504f;    // scale * log2(e)
    __shared__ __attribute__((aligned(16))) unsigned short K_lds[128 * LDK];   // [s][d]
    __shared__ __attribute__((aligned(16))) unsigned short V_lds[64 * LDV];    // [d][s]
    __shared__ __attribute__((aligned(16))) unsigned short P_lds[4][32 * LDP]; // per-wave

    const int tid  = threadIdx.x;
    const int lane = tid & 63, wave = tid >> 6;
    const int g = lane >> 4, li = lane & 15;
    // XCD-grouped bijective decode: bits [0:2]=xcd, [3:5]=sub-head, [6:8]=q-pair
    const int id = blockIdx.x;
    const int bh = (id & 7) * 8 + ((id >> 3) & 7);
    const int qp = id >> 6;                          // 0..7, covers 256 q rows
    const int b = bh >> 4, h = bh & 15;
    const size_t base  = (size_t)b * S * Dm + (size_t)h * DKh;   // [b,s,h,d]
    const size_t vbase = (size_t)bh * DKh * S;                   // [b,h,d,s]
    const int q00 = qp * 256 + wave * 32;            // qt=0 base; qt=1 adds 128

    // Q fragments hoisted to registers (both q-tiles)
    s8v qf[2][2][2];
#pragma unroll
    for (int qt = 0; qt < 2; qt++)
#pragma unroll
        for (int rb = 0; rb < 2; rb++)
#pragma unroll
            for (int ks = 0; ks < 2; ks++)
                qf[qt][rb][ks] = *reinterpret_cast<const s8v*>(
                        Q + base + (size_t)(q00 + qt * 128 + rb * 16 + li) * Dm
                           + ks * 32 + g * 8);

    f4v octx[2][2][4];
    float m_run[2][2][4], l_run[2][2][4];
#pragma unroll
    for (int qt = 0; qt < 2; qt++)
#pragma unroll
        for (int rb = 0; rb < 2; rb++) {
#pragma unroll
            for (int nb = 0; nb < 4; nb++) octx[qt][rb][nb] = (f4v){0.f, 0.f, 0.f, 0.f};
#pragma unroll
            for (int r = 0; r < 4; r++) { m_run[qt][rb][r] = -1e30f; l_run[qt][rb][r] = 0.f; }
        }

    const int rdswz = ((li >> 2) & 3) << 3;          // P_lds read-side XOR key

    for (int t = 0; t < 16; t++) {
        const int kv0 = t * 128;
        __syncthreads();   // protect prev-tile LDS reads
        // ---- stage K [128 s][64 d] and V [64 d][128 s], both vectorized ----
#pragma unroll
        for (int i = 0; i < 4; i++) {
            int e = (i * 256 + tid) * 8;
            int s = e >> 6, d = e & 63;
            *reinterpret_cast<s8v*>(&K_lds[s * LDK + d]) =
                *reinterpret_cast<const s8v*>(K + base + (size_t)(kv0 + s) * Dm + d);
            int dv = e >> 7, sv = e & 127;
            *reinterpret_cast<s8v*>(&V_lds[dv * LDV + sv]) =
                *reinterpret_cast<const s8v*>(Vt + vbase + (size_t)dv * S + kv0 + sv);
        }
        __syncthreads();

#pragma unroll
        for (int qt = 0; qt < 2; qt++) {
            // ---- scores: S = Q @ K^T ----
            f4v sc[2][8];
#pragma unroll
            for (int rb = 0; rb < 2; rb++)
#pragma unroll
                for (int cb = 0; cb < 8; cb++) sc[rb][cb] = (f4v){0.f, 0.f, 0.f, 0.f};
            __builtin_amdgcn_s_setprio(1);
#pragma unroll
            for (int cb = 0; cb < 8; cb++) {
#pragma unroll
                for (int ks = 0; ks < 2; ks++) {
                    s8v kf = *reinterpret_cast<const s8v*>(
                            &K_lds[(cb * 16 + li) * LDK + ks * 32 + g * 8]);
                    sc[0][cb] = MFMA16(qf[qt][0][ks], kf, sc[0][cb]);
                    sc[1][cb] = MFMA16(qf[qt][1][ks], kf, sc[1][cb]);
                }
            }
            __builtin_amdgcn_s_setprio(0);

            // ---- online softmax (exp2 domain) ----
            float rsum[2][4];
#pragma unroll
            for (int rb = 0; rb < 2; rb++) {
                float rmax[4];
#pragma unroll
                for (int r = 0; r < 4; r++) {
                    float v = sc[rb][0][r];
#pragma unroll
                    for (int cb = 1; cb < 8; cb++) v = fmaxf(v, sc[rb][cb][r]);
                    rmax[r] = v * CEXP;
                }
#pragma unroll
                for (int mask = 1; mask < 16; mask <<= 1)
#pragma unroll
                    for (int r = 0; r < 4; r++)
                        rmax[r] = fmaxf(rmax[r], __shfl_xor(rmax[r], mask, 64));
#pragma unroll
                for (int r = 0; r < 4; r++) {
                    float mn = fmaxf(m_run[qt][rb][r], rmax[r]);
                    float scl = __builtin_amdgcn_exp2f(m_run[qt][rb][r] - mn);
                    m_run[qt][rb][r] = mn;
                    l_run[qt][rb][r] *= scl;
                    rsum[rb][r] = 0.f;
#pragma unroll
                    for (int nb = 0; nb < 4; nb++) octx[qt][rb][nb][r] *= scl;
                }
            }

            // ---- P chunks (32 kv cols) interleaved with PV MFMA ----
#pragma unroll
            for (int ks = 0; ks < 4; ks++) {
#pragma unroll
                for (int rb = 0; rb < 2; rb++) {
#pragma unroll
                    for (int cc = 0; cc < 2; cc++) {
                        int cb = ks * 2 + cc;
                        float p0 = __builtin_amdgcn_exp2f(fmaf(sc[rb][cb][0], CEXP, -m_run[qt][rb][0]));
                        float p1 = __builtin_amdgcn_exp2f(fmaf(sc[rb][cb][1], CEXP, -m_run[qt][rb][1]));
                        float p2 = __builtin_amdgcn_exp2f(fmaf(sc[rb][cb][2], CEXP, -m_run[qt][rb][2]));
                        float p3 = __builtin_amdgcn_exp2f(fmaf(sc[rb][cb][3], CEXP, -m_run[qt][rb][3]));
                        rsum[rb][0] += p0; rsum[rb][1] += p1;
                        rsum[rb][2] += p2; rsum[rb][3] += p3;
                        unsigned int u01 = cvt_pk_bf16(p0, p1);
                        unsigned int u23 = cvt_pk_bf16(p2, p3);
                        int rowb = rb * 16 + g * 4;
                        int colS = (cc * 16 + li) ^ (g << 3);   // write-side swizzle
                        P_lds[wave][(rowb + 0) * LDP + colS] = (unsigned short)u01;
                        P_lds[wave][(rowb + 1) * LDP + colS] = (unsigned short)(u01 >> 16);
                        P_lds[wave][(rowb + 2) * LDP + colS] = (unsigned short)u23;
                        P_lds[wave][(rowb + 3) * LDP + colS] = (unsigned short)(u23 >> 16);
                    }
                }
                s8v vf[4], pf[2];
#pragma unroll
                for (int nb = 0; nb < 4; nb++)
                    vf[nb] = *reinterpret_cast<const s8v*>(
                            &V_lds[(nb * 16 + li) * LDV + ks * 32 + g * 8]);
#pragma unroll
                for (int rb = 0; rb < 2; rb++)
                    pf[rb] = *reinterpret_cast<const s8v*>(
                            &P_lds[wave][(rb * 16 + li) * LDP + ((g * 8) ^ rdswz)]);
                __builtin_amdgcn_s_setprio(1);
#pragma unroll
                for (int rb = 0; rb < 2; rb++)
#pragma unroll
                    for (int nb = 0; nb < 4; nb++)
                        octx[qt][rb][nb] = MFMA16(pf[rb], vf[nb], octx[qt][rb][nb]);
                __builtin_amdgcn_s_setprio(0);
            }

            // ---- fold tile sums into running denominators ----
#pragma unroll
            for (int mask = 1; mask < 16; mask <<= 1)
#pragma unroll
                for (int rb = 0; rb < 2; rb++)
#pragma unroll
                    for (int r = 0; r < 4; r++)
                        rsum[rb][r] += __shfl_xor(rsum[rb][r], mask, 64);
#pragma unroll
            for (int rb = 0; rb < 2; rb++)
#pragma unroll
                for (int r = 0; r < 4; r++) l_run[qt][rb][r] += rsum[rb][r];
        }
    }

    // ---- epilogue: normalize, write bf16 ctx in [b,s,h*64+d] layout ----
#pragma unroll
    for (int qt = 0; qt < 2; qt++)
#pragma unroll
        for (int rb = 0; rb < 2; rb++)
#pragma unroll
            for (int r = 0; r < 4; r++) {
                float inv = 1.0f / l_run[qt][rb][r];
                int row = q00 + qt * 128 + rb * 16 + g * 4 + r;
#pragma unroll
                for (int nb = 0; nb < 4; nb++) {
                    int d = nb * 16 + li;
                    Ctx[base + (size_t)row * Dm + d] = f2bf(octx[qt][rb][nb][r] * inv);
                }
            }
}

// ---------------------------------------------------------------------------
extern "C" void kernel_launch(void* const* d_in, const int* in_sizes, int n_in,
                              void* d_out, int out_size, void* d_ws, size_t ws_size,
                              hipStream_t stream) {
    const float* query = (const float*)d_in[0];
    const float* key   = (const float*)d_in[1];
    const float* value = (const float*)d_in[2];
    const float* Wq = (const float*)d_in[3];
    const float* bq = (const float*)d_in[4];
    const float* Wk = (const float*)d_in[5];
    const float* bk = (const float*)d_in[6];
    const float* Wv = (const float*)d_in[7];
    const float* bv = (const float*)d_in[8];
    const float* Wo = (const float*)d_in[9];
    const float* bo = (const float*)d_in[10];

    unsigned short* ws = (unsigned short*)d_ws;
    const size_t MD = (size_t)8192 * 1024;
    unsigned short* Qb  = ws;
    unsigned short* Kb  = Qb + MD;
    unsigned short* Vtb = Kb + MD;   // Vt[b][h][d][s]
    unsigned short* Cb  = Vtb + MD;
    unsigned short* Qx  = Cb + MD;   // bf16 activations
    unsigned short* Kx  = Qx + MD;
    unsigned short* Vx  = Kx + MD;
    unsigned short* Wqt = Vx + MD;
    unsigned short* Wkt = Wqt + 1024 * 1024;
    unsigned short* Wvt = Wkt + 1024 * 1024;
    unsigned short* Wot = Wvt + 1024 * 1024;

    prep_k<<<16384, 256, 0, stream>>>(query, key, value, Qx, Kx, Vx,
                                      Wq, Wk, Wv, Wo, Wqt, Wkt, Wvt, Wot);
    qkv_gemm_k<<<dim3(8, 64, 3), 256, 0, stream>>>(Qx, Kx, Vx, Wqt, Wkt, Wvt,
                                                   bq, bk, bv, Qb, Kb, Vtb);
    attn_k<<<512, 256, 0, stream>>>(Qb, Kb, Vtb, Cb);
    out_gemm_k<<<dim3(8, 64), 256, 0, stream>>>(Cb, Wot, bo, (float*)d_out);
}